// Round 3
// baseline (1124.949 us; speedup 1.0000x reference)
//
#include <hip/hip_runtime.h>
#include <math.h>

// Clockwork RNN, B=512 T=192 DX=32 DH1=256 DH2=512 DY=4
// R2: register-resident MFMA recurrence with shortened critical path.
//  - wave w owns interleaved col tiles {w, w+4, w+8, w+12}*16 -> all waves
//    active every step (NM = NC/64 tiles each).
//  - 3 parallel accumulators (hi*hi, lo*hi, hi*lo) -> 12 indep MFMA chains.
//  - double-buffered h in LDS + copy-forward of non-updated tiles -> ONE
//    __syncthreads per step.
//  - v_cvt_pk_bf16_f32 for all f32->bf16 hi/lo packing; x prefetched 1 step.

#define TT   192
#define DXX  32
#define DH1  256
#define DH2  512
#define NY   4
#define ROWS 16
#define PADK 264   // row stride in shorts; 528B: rotates bank chunks per row

typedef __attribute__((ext_vector_type(8))) short bf16x8;
typedef __attribute__((ext_vector_type(4))) float f32x4;
typedef __attribute__((ext_vector_type(2))) int   i32x2;
typedef __attribute__((ext_vector_type(4))) int   i32x4;

template<int N> struct IC { static constexpr int v = N; };

__device__ __forceinline__ short f2bf(float f) {
    unsigned u = __float_as_uint(f);
    unsigned rr = (u + 0x7FFFu + ((u >> 16) & 1u)) >> 16;
    return (short)rr;
}
__device__ __forceinline__ float bf2f(short h) {
    return __uint_as_float(((unsigned)(unsigned short)h) << 16);
}
__device__ __forceinline__ unsigned cvtpk(float a, float b) {
    unsigned d;
    asm("v_cvt_pk_bf16_f32 %0, %1, %2" : "=v"(d) : "v"(a), "v"(b));
    return d;   // lo16 = bf16(a), hi16 = bf16(b)
}
__device__ __forceinline__ float fast_tanh(float v) {
    float t = __builtin_amdgcn_exp2f(v * 2.885390081777927f);
    return fmaf(-2.f, __builtin_amdgcn_rcpf(t + 1.f), 1.f);
}

__global__ __launch_bounds__(256, 1) void cwrnn_mfma2(
    const float* __restrict__ x,     // [B,T,DX]
    const float* __restrict__ w_x,   // [DY,DX,DH1]
    const float* __restrict__ w_h,   // [DY,DH1,DH1]
    const float* __restrict__ bias,  // [DY,DH1]
    const float* __restrict__ W1,    // [DY,DH1,DH2]
    const float* __restrict__ b1,    // [DY,DH2]
    const float* __restrict__ W2,    // [DY,DH2]
    const float* __restrict__ b2,    // [DY]
    float* __restrict__ out)         // [B,DY]
{
    __shared__ short hb_hi[2][ROWS * PADK];   // h bf16 hi, [buf][row][k]
    __shared__ short hb_lo[2][ROWS * PADK];   // h bf16 lo
    __shared__ float scratch[DXX * DH1];      // 32KB staging; reused as hT
    __shared__ float red[4][ROWS];

    const int t    = threadIdx.x;
    const int lane = t & 63;
    const int w    = t >> 6;
    const int r    = lane & 15;
    const int q    = lane >> 4;
    const int y    = blockIdx.x & 3;
    const int b0   = (blockIdx.x >> 2) * ROWS;

    const float* wx_g = w_x + (size_t)y * DXX * DH1;
    const float* wh_g = w_h + (size_t)y * DH1 * DH1;

    for (int i = t; i < ROWS * PADK; i += 256) { hb_hi[0][i] = 0; hb_lo[0][i] = 0; }

    // ---- w_x fragments (interleaved col tiles: tile m -> cols (m*4+w)*16) ----
    bf16x8 wxh[4], wxl[4];
    for (int i = t * 4; i < DXX * DH1; i += 1024)
        *(f32x4*)&scratch[i] = *(const f32x4*)&wx_g[i];
    __syncthreads();
    #pragma unroll
    for (int m = 0; m < 4; ++m) {
        bf16x8 vh, vl;
        #pragma unroll
        for (int jj = 0; jj < 8; ++jj) {
            float v = scratch[(q * 8 + jj) * DH1 + ((m * 4 + w) << 4) + r];
            short hi = f2bf(v);
            vh[jj] = hi; vl[jj] = f2bf(v - bf2f(hi));
        }
        wxh[m] = vh; wxl[m] = vl;
    }
    __syncthreads();

    // ---- w_h fragments: 8 ktiles x 4 mtiles, hi/lo ----
    bf16x8 whh[8][4], whl[8][4];
    for (int kt = 0; kt < 8; ++kt) {
        for (int i = t * 4; i < 32 * DH1; i += 1024)
            *(f32x4*)&scratch[i] = *(const f32x4*)&wh_g[kt * 32 * DH1 + i];
        __syncthreads();
        #pragma unroll
        for (int m = 0; m < 4; ++m) {
            bf16x8 vh, vl;
            #pragma unroll
            for (int jj = 0; jj < 8; ++jj) {
                float v = scratch[(q * 8 + jj) * DH1 + ((m * 4 + w) << 4) + r];
                short hi = f2bf(v);
                vh[jj] = hi; vl[jj] = f2bf(v - bf2f(hi));
            }
            whh[kt][m] = vh; whl[kt][m] = vl;
        }
        __syncthreads();
    }

    f32x4 bias4[4];
    #pragma unroll
    for (int m = 0; m < 4; ++m)
        #pragma unroll
        for (int rr = 0; rr < 4; ++rr)
            bias4[m][rr] = bias[y * DH1 + ((m * 4 + w) << 4) + q * 4 + rr];

    const float* xrow = x + (size_t)(b0 + r) * TT * DXX + q * 8;
    f32x4 cxa = *(const f32x4*)&xrow[0];
    f32x4 cxb = *(const f32x4*)&xrow[4];

    int cur = 0;

    auto body = [&](int j, auto NMC) {
        constexpr int NM = NMC.v;                 // active mtiles per wave
        constexpr int NF = (NM == 2) ? 16 : (NM == 3) ? 24 : 32;

        short* rh_hi = hb_hi[cur];     short* rh_lo = hb_lo[cur];
        short* nh_hi = hb_hi[cur ^ 1]; short* nh_lo = hb_lo[cur ^ 1];

        // prefetch next step's x
        const int jn = (j + 1 < TT) ? j + 1 : j;
        const f32x4 pxa = *(const f32x4*)&xrow[jn * DXX];
        const f32x4 pxb = *(const f32x4*)&xrow[jn * DXX + 4];

        f32x4 aA[4], aB[4], aC[4];
        #pragma unroll
        for (int m = 0; m < NM; ++m) {
            aA[m] = bias4[m];
            aB[m] = (f32x4){0.f, 0.f, 0.f, 0.f};
            aC[m] = (f32x4){0.f, 0.f, 0.f, 0.f};
        }

        #pragma unroll
        for (int kt = 0; kt < 8; ++kt) {
            const int ro = r * PADK + kt * 32 + q * 8;
            const bf16x8 bhi = *(const bf16x8*)&rh_hi[ro];
            const bf16x8 blo = *(const bf16x8*)&rh_lo[ro];
            #pragma unroll
            for (int m = 0; m < NM; ++m) {
                aA[m] = __builtin_amdgcn_mfma_f32_16x16x32_bf16(whh[kt][m], bhi, aA[m], 0, 0, 0);
                aB[m] = __builtin_amdgcn_mfma_f32_16x16x32_bf16(whl[kt][m], bhi, aB[m], 0, 0, 0);
                aC[m] = __builtin_amdgcn_mfma_f32_16x16x32_bf16(whh[kt][m], blo, aC[m], 0, 0, 0);
            }
        }

        // x term (feature mask: quads with q*8 >= NF contribute zero)
        bf16x8 xhi = {0,0,0,0,0,0,0,0}, xlo = {0,0,0,0,0,0,0,0};
        if (q * 8 < NF) {
            unsigned p0 = cvtpk(cxa[0], cxa[1]), p1 = cvtpk(cxa[2], cxa[3]);
            unsigned p2 = cvtpk(cxb[0], cxb[1]), p3 = cvtpk(cxb[2], cxb[3]);
            float g0 = __uint_as_float(p0 << 16), g1 = __uint_as_float(p0 & 0xffff0000u);
            float g2 = __uint_as_float(p1 << 16), g3 = __uint_as_float(p1 & 0xffff0000u);
            float g4 = __uint_as_float(p2 << 16), g5 = __uint_as_float(p2 & 0xffff0000u);
            float g6 = __uint_as_float(p3 << 16), g7 = __uint_as_float(p3 & 0xffff0000u);
            unsigned l0 = cvtpk(cxa[0] - g0, cxa[1] - g1);
            unsigned l1 = cvtpk(cxa[2] - g2, cxa[3] - g3);
            unsigned l2 = cvtpk(cxb[0] - g4, cxb[1] - g5);
            unsigned l3 = cvtpk(cxb[2] - g6, cxb[3] - g7);
            union { i32x4 i; bf16x8 h; } uh, ul;
            uh.i = (i32x4){(int)p0, (int)p1, (int)p2, (int)p3};
            ul.i = (i32x4){(int)l0, (int)l1, (int)l2, (int)l3};
            xhi = uh.h; xlo = ul.h;
        }
        #pragma unroll
        for (int m = 0; m < NM; ++m) {
            aA[m] = __builtin_amdgcn_mfma_f32_16x16x32_bf16(wxh[m], xhi, aA[m], 0, 0, 0);
            aB[m] = __builtin_amdgcn_mfma_f32_16x16x32_bf16(wxl[m], xhi, aB[m], 0, 0, 0);
            aC[m] = __builtin_amdgcn_mfma_f32_16x16x32_bf16(wxh[m], xlo, aC[m], 0, 0, 0);
        }

        // epilogue: merge, tanh, pack hi/lo, write to next buffer
        #pragma unroll
        for (int m = 0; m < NM; ++m) {
            const f32x4 s = aA[m] + aB[m] + aC[m];
            const float t0 = fast_tanh(s[0]), t1 = fast_tanh(s[1]);
            const float t2 = fast_tanh(s[2]), t3 = fast_tanh(s[3]);
            unsigned hp0 = cvtpk(t0, t1), hp1 = cvtpk(t2, t3);
            float g0 = __uint_as_float(hp0 << 16), g1 = __uint_as_float(hp0 & 0xffff0000u);
            float g2 = __uint_as_float(hp1 << 16), g3 = __uint_as_float(hp1 & 0xffff0000u);
            unsigned lp0 = cvtpk(t0 - g0, t1 - g1), lp1 = cvtpk(t2 - g2, t3 - g3);
            const int off = r * PADK + ((m * 4 + w) << 4) + q * 4;
            *(i32x2*)&nh_hi[off] = (i32x2){(int)hp0, (int)hp1};
            *(i32x2*)&nh_lo[off] = (i32x2){(int)lp0, (int)lp1};
        }
        // copy-forward non-updated tiles (clockwork carry)
        #pragma unroll
        for (int m = NM; m < 4; ++m) {
            const int off = r * PADK + ((m * 4 + w) << 4) + q * 4;
            *(i32x2*)&nh_hi[off] = *(const i32x2*)&rh_hi[off];
            *(i32x2*)&nh_lo[off] = *(const i32x2*)&rh_lo[off];
        }
        __syncthreads();
        cur ^= 1;
        cxa = pxa; cxb = pxb;
    };

    for (int j = 0; j < TT; j += 4) {
        body(j + 0, IC<2>{});   // jp%2==1            -> NC=128
        body(j + 1, IC<3>{});   // jp%2==0, jp%4!=0   -> NC=192
        body(j + 2, IC<2>{});   // jp%2==1            -> NC=128
        body(j + 3, IC<4>{});   // jp%4==0            -> NC=256
    }
    // after 192 steps, final h is in buffer 0

    // ---- rebuild h fp32, transposed [k][row] (reuse scratch) ----
    float* hT = scratch;
    for (int i = t; i < DH1 * ROWS; i += 256) {
        const int row = i & 15, k = i >> 4;
        hT[k * ROWS + row] = bf2f(hb_hi[0][row * PADK + k]) + bf2f(hb_lo[0][row * PADK + k]);
    }
    __syncthreads();

    // ---- head: hid = relu(h @ W1 + b1); y = hid @ W2 + b2 ----
    const float* W1_g = W1 + (size_t)y * DH1 * DH2;
    const int e0 = 2 * t;
    float a0[16], a1[16];
    #pragma unroll
    for (int m = 0; m < 16; ++m) { a0[m] = 0.f; a1[m] = 0.f; }
    for (int k = 0; k < DH1; ++k) {
        const float2 wv = *(const float2*)&W1_g[(size_t)k * DH2 + e0];
        const f32x4* hp = (const f32x4*)&hT[k * ROWS];
        #pragma unroll
        for (int g = 0; g < 4; ++g) {
            const f32x4 hv = hp[g];
            a0[g * 4 + 0] += hv[0] * wv.x; a0[g * 4 + 1] += hv[1] * wv.x;
            a0[g * 4 + 2] += hv[2] * wv.x; a0[g * 4 + 3] += hv[3] * wv.x;
            a1[g * 4 + 0] += hv[0] * wv.y; a1[g * 4 + 1] += hv[1] * wv.y;
            a1[g * 4 + 2] += hv[2] * wv.y; a1[g * 4 + 3] += hv[3] * wv.y;
        }
    }
    {
        const float b1a = b1[y * DH2 + e0], b1b = b1[y * DH2 + e0 + 1];
        const float w2a = W2[y * DH2 + e0], w2b = W2[y * DH2 + e0 + 1];
        float p[16];
        #pragma unroll
        for (int m = 0; m < 16; ++m)
            p[m] = fmaxf(a0[m] + b1a, 0.f) * w2a + fmaxf(a1[m] + b1b, 0.f) * w2b;
        #pragma unroll
        for (int m = 0; m < 16; ++m) {
            float v = p[m];
            for (int off = 32; off > 0; off >>= 1) v += __shfl_down(v, off);
            if (lane == 0) red[w][m] = v;
        }
    }
    __syncthreads();
    if (t < ROWS) {
        out[(size_t)(b0 + t) * NY + y] =
            red[0][t] + red[1][t] + red[2][t] + red[3][t] + b2[y];
    }
}

extern "C" void kernel_launch(void* const* d_in, const int* in_sizes, int n_in,
                              void* d_out, int out_size, void* d_ws, size_t ws_size,
                              hipStream_t stream) {
    const float* x   = (const float*)d_in[0];
    const float* w_x = (const float*)d_in[1];
    const float* w_h = (const float*)d_in[2];
    const float* b   = (const float*)d_in[3];
    const float* W1  = (const float*)d_in[4];
    const float* b1  = (const float*)d_in[5];
    const float* W2  = (const float*)d_in[6];
    const float* b2  = (const float*)d_in[7];
    float* out = (float*)d_out;

    dim3 grid(128), block(256);
    hipLaunchKernelGGL(cwrnn_mfma2, grid, block, 0, stream,
                       x, w_x, w_h, b, W1, b1, W2, b2, out);
}

// Round 4
// 289.497 us; speedup vs baseline: 3.8859x; 3.8859x over previous
//
#include <hip/hip_runtime.h>
#include <math.h>

// Clockwork RNN, B=512 T=192 DX=32 DH1=256 DH2=512 DY=4
// R3 = R2 schedule with the register-residency bug fixed: the w_h fragment
// gather loop MUST be fully unrolled (compile-time indices) or the fragment
// arrays demote to scratch (R2: VGPR=92, FETCH 215MB, 1125us).
//  - wave w owns interleaved col tiles {w, w+4, w+8, w+12}*16 -> all waves
//    active every step (NM = NC/64 tiles each).
//  - 3 parallel accumulators (hi*hi, lo*hi, hi*lo) -> 12 indep MFMA chains.
//  - double-buffered h in LDS + copy-forward of non-updated tiles -> ONE
//    __syncthreads per step.
//  - v_cvt_pk_bf16_f32 packing; x prefetched 1 step ahead.

#define TT   192
#define DXX  32
#define DH1  256
#define DH2  512
#define NY   4
#define ROWS 16
#define PADK 264   // row stride in shorts; 528B: rotates bank chunks per row

typedef __attribute__((ext_vector_type(8))) short bf16x8;
typedef __attribute__((ext_vector_type(4))) float f32x4;
typedef __attribute__((ext_vector_type(2))) int   i32x2;
typedef __attribute__((ext_vector_type(4))) int   i32x4;

template<int N> struct IC { static constexpr int v = N; };

__device__ __forceinline__ short f2bf(float f) {
    unsigned u = __float_as_uint(f);
    unsigned rr = (u + 0x7FFFu + ((u >> 16) & 1u)) >> 16;
    return (short)rr;
}
__device__ __forceinline__ float bf2f(short h) {
    return __uint_as_float(((unsigned)(unsigned short)h) << 16);
}
__device__ __forceinline__ unsigned cvtpk(float a, float b) {
    unsigned d;
    asm("v_cvt_pk_bf16_f32 %0, %1, %2" : "=v"(d) : "v"(a), "v"(b));
    return d;   // lo16 = bf16(a), hi16 = bf16(b)
}
__device__ __forceinline__ float fast_tanh(float v) {
    float t = __builtin_amdgcn_exp2f(v * 2.885390081777927f);
    return fmaf(-2.f, __builtin_amdgcn_rcpf(t + 1.f), 1.f);
}

__global__ __launch_bounds__(256, 1) void cwrnn_mfma3(
    const float* __restrict__ x,     // [B,T,DX]
    const float* __restrict__ w_x,   // [DY,DX,DH1]
    const float* __restrict__ w_h,   // [DY,DH1,DH1]
    const float* __restrict__ bias,  // [DY,DH1]
    const float* __restrict__ W1,    // [DY,DH1,DH2]
    const float* __restrict__ b1,    // [DY,DH2]
    const float* __restrict__ W2,    // [DY,DH2]
    const float* __restrict__ b2,    // [DY]
    float* __restrict__ out)         // [B,DY]
{
    __shared__ short hb_hi[2][ROWS * PADK];   // h bf16 hi, [buf][row][k]
    __shared__ short hb_lo[2][ROWS * PADK];   // h bf16 lo
    __shared__ float scratch[DXX * DH1];      // 32KB staging; reused as hT
    __shared__ float red[4][ROWS];

    const int t    = threadIdx.x;
    const int lane = t & 63;
    const int w    = t >> 6;
    const int r    = lane & 15;
    const int q    = lane >> 4;
    const int y    = blockIdx.x & 3;
    const int b0   = (blockIdx.x >> 2) * ROWS;

    const float* wx_g = w_x + (size_t)y * DXX * DH1;
    const float* wh_g = w_h + (size_t)y * DH1 * DH1;

    for (int i = t; i < ROWS * PADK; i += 256) { hb_hi[0][i] = 0; hb_lo[0][i] = 0; }

    // ---- w_x fragments (interleaved col tiles: tile m -> cols (m*4+w)*16) ----
    bf16x8 wxh[4], wxl[4];
    for (int i = t * 4; i < DXX * DH1; i += 1024)
        *(f32x4*)&scratch[i] = *(const f32x4*)&wx_g[i];
    __syncthreads();
    #pragma unroll
    for (int m = 0; m < 4; ++m) {
        bf16x8 vh, vl;
        #pragma unroll
        for (int jj = 0; jj < 8; ++jj) {
            float v = scratch[(q * 8 + jj) * DH1 + ((m * 4 + w) << 4) + r];
            short hi = f2bf(v);
            vh[jj] = hi; vl[jj] = f2bf(v - bf2f(hi));
        }
        wxh[m] = vh; wxl[m] = vl;
    }
    __syncthreads();

    // ---- w_h fragments: 8 ktiles x 4 mtiles, hi/lo.
    // MUST be fully unrolled: runtime kt would demote whh/whl to scratch
    // (R2 lesson: VGPR 92, FETCH 215MB, 2.3x regression).
    bf16x8 whh[8][4], whl[8][4];
    #pragma unroll
    for (int kt = 0; kt < 8; ++kt) {
        for (int i = t * 4; i < 32 * DH1; i += 1024)
            *(f32x4*)&scratch[i] = *(const f32x4*)&wh_g[kt * 32 * DH1 + i];
        __syncthreads();
        #pragma unroll
        for (int m = 0; m < 4; ++m) {
            bf16x8 vh, vl;
            #pragma unroll
            for (int jj = 0; jj < 8; ++jj) {
                float v = scratch[(q * 8 + jj) * DH1 + ((m * 4 + w) << 4) + r];
                short hi = f2bf(v);
                vh[jj] = hi; vl[jj] = f2bf(v - bf2f(hi));
            }
            whh[kt][m] = vh; whl[kt][m] = vl;
        }
        __syncthreads();
    }

    f32x4 bias4[4];
    #pragma unroll
    for (int m = 0; m < 4; ++m)
        #pragma unroll
        for (int rr = 0; rr < 4; ++rr)
            bias4[m][rr] = bias[y * DH1 + ((m * 4 + w) << 4) + q * 4 + rr];

    const float* xrow = x + (size_t)(b0 + r) * TT * DXX + q * 8;
    f32x4 cxa = *(const f32x4*)&xrow[0];
    f32x4 cxb = *(const f32x4*)&xrow[4];

    int cur = 0;

    auto body = [&](int j, auto NMC) {
        constexpr int NM = NMC.v;                 // active mtiles per wave
        constexpr int NF = (NM == 2) ? 16 : (NM == 3) ? 24 : 32;

        short* rh_hi = hb_hi[cur];     short* rh_lo = hb_lo[cur];
        short* nh_hi = hb_hi[cur ^ 1]; short* nh_lo = hb_lo[cur ^ 1];

        // prefetch next step's x
        const int jn = (j + 1 < TT) ? j + 1 : j;
        const f32x4 pxa = *(const f32x4*)&xrow[jn * DXX];
        const f32x4 pxb = *(const f32x4*)&xrow[jn * DXX + 4];

        f32x4 aA[NM], aB[NM], aC[NM];
        #pragma unroll
        for (int m = 0; m < NM; ++m) {
            aA[m] = bias4[m];
            aB[m] = (f32x4){0.f, 0.f, 0.f, 0.f};
            aC[m] = (f32x4){0.f, 0.f, 0.f, 0.f};
        }

        #pragma unroll
        for (int kt = 0; kt < 8; ++kt) {
            const int ro = r * PADK + kt * 32 + q * 8;
            const bf16x8 bhi = *(const bf16x8*)&rh_hi[ro];
            const bf16x8 blo = *(const bf16x8*)&rh_lo[ro];
            #pragma unroll
            for (int m = 0; m < NM; ++m) {
                aA[m] = __builtin_amdgcn_mfma_f32_16x16x32_bf16(whh[kt][m], bhi, aA[m], 0, 0, 0);
                aB[m] = __builtin_amdgcn_mfma_f32_16x16x32_bf16(whl[kt][m], bhi, aB[m], 0, 0, 0);
                aC[m] = __builtin_amdgcn_mfma_f32_16x16x32_bf16(whh[kt][m], blo, aC[m], 0, 0, 0);
            }
        }

        // x term (feature mask: quads with q*8 >= NF contribute zero)
        bf16x8 xhi = {0,0,0,0,0,0,0,0}, xlo = {0,0,0,0,0,0,0,0};
        if (q * 8 < NF) {
            unsigned p0 = cvtpk(cxa[0], cxa[1]), p1 = cvtpk(cxa[2], cxa[3]);
            unsigned p2 = cvtpk(cxb[0], cxb[1]), p3 = cvtpk(cxb[2], cxb[3]);
            float g0 = __uint_as_float(p0 << 16), g1 = __uint_as_float(p0 & 0xffff0000u);
            float g2 = __uint_as_float(p1 << 16), g3 = __uint_as_float(p1 & 0xffff0000u);
            float g4 = __uint_as_float(p2 << 16), g5 = __uint_as_float(p2 & 0xffff0000u);
            float g6 = __uint_as_float(p3 << 16), g7 = __uint_as_float(p3 & 0xffff0000u);
            unsigned l0 = cvtpk(cxa[0] - g0, cxa[1] - g1);
            unsigned l1 = cvtpk(cxa[2] - g2, cxa[3] - g3);
            unsigned l2 = cvtpk(cxb[0] - g4, cxb[1] - g5);
            unsigned l3 = cvtpk(cxb[2] - g6, cxb[3] - g7);
            union { i32x4 i; bf16x8 h; } uh, ul;
            uh.i = (i32x4){(int)p0, (int)p1, (int)p2, (int)p3};
            ul.i = (i32x4){(int)l0, (int)l1, (int)l2, (int)l3};
            xhi = uh.h; xlo = ul.h;
        }
        #pragma unroll
        for (int m = 0; m < NM; ++m) {
            aA[m] = __builtin_amdgcn_mfma_f32_16x16x32_bf16(wxh[m], xhi, aA[m], 0, 0, 0);
            aB[m] = __builtin_amdgcn_mfma_f32_16x16x32_bf16(wxl[m], xhi, aB[m], 0, 0, 0);
            aC[m] = __builtin_amdgcn_mfma_f32_16x16x32_bf16(wxh[m], xlo, aC[m], 0, 0, 0);
        }

        // epilogue: merge, tanh, pack hi/lo, write to next buffer
        #pragma unroll
        for (int m = 0; m < NM; ++m) {
            const f32x4 s = aA[m] + aB[m] + aC[m];
            const float t0 = fast_tanh(s[0]), t1 = fast_tanh(s[1]);
            const float t2 = fast_tanh(s[2]), t3 = fast_tanh(s[3]);
            unsigned hp0 = cvtpk(t0, t1), hp1 = cvtpk(t2, t3);
            float g0 = __uint_as_float(hp0 << 16), g1 = __uint_as_float(hp0 & 0xffff0000u);
            float g2 = __uint_as_float(hp1 << 16), g3 = __uint_as_float(hp1 & 0xffff0000u);
            unsigned lp0 = cvtpk(t0 - g0, t1 - g1), lp1 = cvtpk(t2 - g2, t3 - g3);
            const int off = r * PADK + ((m * 4 + w) << 4) + q * 4;
            *(i32x2*)&nh_hi[off] = (i32x2){(int)hp0, (int)hp1};
            *(i32x2*)&nh_lo[off] = (i32x2){(int)lp0, (int)lp1};
        }
        // copy-forward non-updated tiles (clockwork carry)
        #pragma unroll
        for (int m = NM; m < 4; ++m) {
            const int off = r * PADK + ((m * 4 + w) << 4) + q * 4;
            *(i32x2*)&nh_hi[off] = *(const i32x2*)&rh_hi[off];
            *(i32x2*)&nh_lo[off] = *(const i32x2*)&rh_lo[off];
        }
        __syncthreads();
        cur ^= 1;
        cxa = pxa; cxb = pxb;
    };

    for (int j = 0; j < TT; j += 4) {
        body(j + 0, IC<2>{});   // jp%2==1            -> NC=128
        body(j + 1, IC<3>{});   // jp%2==0, jp%4!=0   -> NC=192
        body(j + 2, IC<2>{});   // jp%2==1            -> NC=128
        body(j + 3, IC<4>{});   // jp%4==0            -> NC=256
    }
    // after 192 steps, final h is in buffer 0

    // ---- rebuild h fp32, transposed [k][row] (reuse scratch) ----
    float* hT = scratch;
    for (int i = t; i < DH1 * ROWS; i += 256) {
        const int row = i & 15, k = i >> 4;
        hT[k * ROWS + row] = bf2f(hb_hi[0][row * PADK + k]) + bf2f(hb_lo[0][row * PADK + k]);
    }
    __syncthreads();

    // ---- head: hid = relu(h @ W1 + b1); y = hid @ W2 + b2 ----
    const float* W1_g = W1 + (size_t)y * DH1 * DH2;
    const int e0 = 2 * t;
    float a0[16], a1[16];
    #pragma unroll
    for (int m = 0; m < 16; ++m) { a0[m] = 0.f; a1[m] = 0.f; }
    for (int k = 0; k < DH1; ++k) {
        const float2 wv = *(const float2*)&W1_g[(size_t)k * DH2 + e0];
        const f32x4* hp = (const f32x4*)&hT[k * ROWS];
        #pragma unroll
        for (int g = 0; g < 4; ++g) {
            const f32x4 hv = hp[g];
            a0[g * 4 + 0] += hv[0] * wv.x; a0[g * 4 + 1] += hv[1] * wv.x;
            a0[g * 4 + 2] += hv[2] * wv.x; a0[g * 4 + 3] += hv[3] * wv.x;
            a1[g * 4 + 0] += hv[0] * wv.y; a1[g * 4 + 1] += hv[1] * wv.y;
            a1[g * 4 + 2] += hv[2] * wv.y; a1[g * 4 + 3] += hv[3] * wv.y;
        }
    }
    {
        const float b1a = b1[y * DH2 + e0], b1b = b1[y * DH2 + e0 + 1];
        const float w2a = W2[y * DH2 + e0], w2b = W2[y * DH2 + e0 + 1];
        float p[16];
        #pragma unroll
        for (int m = 0; m < 16; ++m)
            p[m] = fmaxf(a0[m] + b1a, 0.f) * w2a + fmaxf(a1[m] + b1b, 0.f) * w2b;
        #pragma unroll
        for (int m = 0; m < 16; ++m) {
            float v = p[m];
            for (int off = 32; off > 0; off >>= 1) v += __shfl_down(v, off);
            if (lane == 0) red[w][m] = v;
        }
    }
    __syncthreads();
    if (t < ROWS) {
        out[(size_t)(b0 + t) * NY + y] =
            red[0][t] + red[1][t] + red[2][t] + red[3][t] + b2[y];
    }
}

extern "C" void kernel_launch(void* const* d_in, const int* in_sizes, int n_in,
                              void* d_out, int out_size, void* d_ws, size_t ws_size,
                              hipStream_t stream) {
    const float* x   = (const float*)d_in[0];
    const float* w_x = (const float*)d_in[1];
    const float* w_h = (const float*)d_in[2];
    const float* b   = (const float*)d_in[3];
    const float* W1  = (const float*)d_in[4];
    const float* b1  = (const float*)d_in[5];
    const float* W2  = (const float*)d_in[6];
    const float* b2  = (const float*)d_in[7];
    float* out = (float*)d_out;

    dim3 grid(128), block(256);
    hipLaunchKernelGGL(cwrnn_mfma3, grid, block, 0, stream,
                       x, w_x, w_h, b, W1, b1, W2, b2, out);
}

// Round 5
// 238.663 us; speedup vs baseline: 4.7135x; 1.2130x over previous
//
#include <hip/hip_runtime.h>
#include <math.h>

// Clockwork RNN, B=512 T=192 DX=32 DH1=256 DH2=512 DY=4
// R4: 256 blocks (8 batch rows x one y) x 8 waves (512 thr) -> 2 waves/SIMD
// on all 256 CUs. Wave w owns col tiles {w, 8+w}. w_h bf16 hi/lo fragments
// register-resident (~144 VGPR, launch_bounds(512,2)). h in LDS rows 0..7;
// B-fragment lanes r and r+8 broadcast-read the same row (8 unique rows).
// 3 parallel accumulator chains, 1 barrier/step, cvt_pk packing, x prefetch.

#define TT    192
#define DXX   32
#define DH1   256
#define DH2   512
#define NY    4
#define ROWS8 8
#define PADK  264   // row stride in shorts (528B); read floor 4cy, benign

typedef __attribute__((ext_vector_type(8))) short bf16x8;
typedef __attribute__((ext_vector_type(4))) float f32x4;
typedef __attribute__((ext_vector_type(2))) int   i32x2;
typedef __attribute__((ext_vector_type(4))) int   i32x4;

template<int N> struct IC { static constexpr int v = N; };

__device__ __forceinline__ short f2bf(float f) {
    unsigned u = __float_as_uint(f);
    unsigned rr = (u + 0x7FFFu + ((u >> 16) & 1u)) >> 16;
    return (short)rr;
}
__device__ __forceinline__ float bf2f(short h) {
    return __uint_as_float(((unsigned)(unsigned short)h) << 16);
}
__device__ __forceinline__ unsigned cvtpk(float a, float b) {
    unsigned d;
    asm("v_cvt_pk_bf16_f32 %0, %1, %2" : "=v"(d) : "v"(a), "v"(b));
    return d;   // lo16 = bf16(a), hi16 = bf16(b)
}
__device__ __forceinline__ float fast_tanh(float v) {
    float t = __builtin_amdgcn_exp2f(v * 2.885390081777927f);
    return fmaf(-2.f, __builtin_amdgcn_rcpf(t + 1.f), 1.f);
}

__global__ __launch_bounds__(512, 2) void cwrnn_mfma4(
    const float* __restrict__ x,     // [B,T,DX]
    const float* __restrict__ w_x,   // [DY,DX,DH1]
    const float* __restrict__ w_h,   // [DY,DH1,DH1]
    const float* __restrict__ bias,  // [DY,DH1]
    const float* __restrict__ W1,    // [DY,DH1,DH2]
    const float* __restrict__ b1,    // [DY,DH2]
    const float* __restrict__ W2,    // [DY,DH2]
    const float* __restrict__ b2,    // [DY]
    float* __restrict__ out)         // [B,DY]
{
    __shared__ short hb_hi[2][ROWS8 * PADK];  // h bf16 hi, [buf][row][k]
    __shared__ short hb_lo[2][ROWS8 * PADK];  // h bf16 lo
    __shared__ float scratch[DXX * DH1];      // 32KB staging; reused as hT
    __shared__ float red[8][ROWS8];

    const int t    = threadIdx.x;
    const int lane = t & 63;
    const int w    = t >> 6;        // wave 0..7
    const int r    = lane & 15;
    const int rb   = r & 7;         // batch row within block
    const int q    = lane >> 4;
    const int y    = blockIdx.x & 3;
    const int b0   = (blockIdx.x >> 2) * ROWS8;

    const float* wx_g = w_x + (size_t)y * DXX * DH1;
    const float* wh_g = w_h + (size_t)y * DH1 * DH1;

    for (int i = t; i < ROWS8 * PADK; i += 512) { hb_hi[0][i] = 0; hb_lo[0][i] = 0; }

    // ---- w_x fragments: wave w -> tiles {w, 8+w} (tile = 16 cols) ----
    bf16x8 wxh[2], wxl[2];
    for (int i = t * 4; i < DXX * DH1; i += 2048)
        *(f32x4*)&scratch[i] = *(const f32x4*)&wx_g[i];
    __syncthreads();
    #pragma unroll
    for (int m = 0; m < 2; ++m) {
        bf16x8 vh, vl;
        #pragma unroll
        for (int jj = 0; jj < 8; ++jj) {
            float v = scratch[(q * 8 + jj) * DH1 + ((m * 8 + w) << 4) + r];
            short hi = f2bf(v);
            vh[jj] = hi; vl[jj] = f2bf(v - bf2f(hi));
        }
        wxh[m] = vh; wxl[m] = vl;
    }
    __syncthreads();

    // ---- w_h fragments: 8 ktiles x 2 mtiles, hi/lo. FULLY UNROLLED
    // (runtime index -> scratch demotion; R2 lesson). ----
    bf16x8 whh[8][2], whl[8][2];
    #pragma unroll
    for (int kt = 0; kt < 8; ++kt) {
        for (int i = t * 4; i < 32 * DH1; i += 2048)
            *(f32x4*)&scratch[i] = *(const f32x4*)&wh_g[kt * 32 * DH1 + i];
        __syncthreads();
        #pragma unroll
        for (int m = 0; m < 2; ++m) {
            bf16x8 vh, vl;
            #pragma unroll
            for (int jj = 0; jj < 8; ++jj) {
                float v = scratch[(q * 8 + jj) * DH1 + ((m * 8 + w) << 4) + r];
                short hi = f2bf(v);
                vh[jj] = hi; vl[jj] = f2bf(v - bf2f(hi));
            }
            whh[kt][m] = vh; whl[kt][m] = vl;
        }
        __syncthreads();
    }

    f32x4 bias4[2];
    #pragma unroll
    for (int m = 0; m < 2; ++m)
        #pragma unroll
        for (int rr = 0; rr < 4; ++rr)
            bias4[m][rr] = bias[y * DH1 + ((m * 8 + w) << 4) + q * 4 + rr];

    const float* xrow = x + (size_t)(b0 + rb) * TT * DXX + q * 8;
    f32x4 cxa = *(const f32x4*)&xrow[0];
    f32x4 cxb = *(const f32x4*)&xrow[4];

    int cur = 0;

    // S: 0 -> NC=128 (m0 only), 1 -> NC=192 (m1 iff w<4), 2 -> NC=256 (both)
    auto body = [&](int j, auto SC) {
        constexpr int S  = SC.v;
        constexpr int NF = (S == 0) ? 16 : (S == 1) ? 24 : 32;
        const bool m1act = (S == 2) || (S == 1 && w < 4);

        short* rh_hi = hb_hi[cur];     short* rh_lo = hb_lo[cur];
        short* nh_hi = hb_hi[cur ^ 1]; short* nh_lo = hb_lo[cur ^ 1];

        const int jn = (j + 1 < TT) ? j + 1 : j;
        const f32x4 pxa = *(const f32x4*)&xrow[jn * DXX];
        const f32x4 pxb = *(const f32x4*)&xrow[jn * DXX + 4];

        f32x4 aA0 = bias4[0], aB0 = {0,0,0,0}, aC0 = {0,0,0,0};
        f32x4 aA1 = bias4[1], aB1 = {0,0,0,0}, aC1 = {0,0,0,0};

        #pragma unroll
        for (int kt = 0; kt < 8; ++kt) {
            const int ro = rb * PADK + kt * 32 + q * 8;
            const bf16x8 bhi = *(const bf16x8*)&rh_hi[ro];
            const bf16x8 blo = *(const bf16x8*)&rh_lo[ro];
            aA0 = __builtin_amdgcn_mfma_f32_16x16x32_bf16(whh[kt][0], bhi, aA0, 0, 0, 0);
            aB0 = __builtin_amdgcn_mfma_f32_16x16x32_bf16(whl[kt][0], bhi, aB0, 0, 0, 0);
            aC0 = __builtin_amdgcn_mfma_f32_16x16x32_bf16(whh[kt][0], blo, aC0, 0, 0, 0);
            if (S == 2 || (S == 1 && m1act)) {
                aA1 = __builtin_amdgcn_mfma_f32_16x16x32_bf16(whh[kt][1], bhi, aA1, 0, 0, 0);
                aB1 = __builtin_amdgcn_mfma_f32_16x16x32_bf16(whl[kt][1], bhi, aB1, 0, 0, 0);
                aC1 = __builtin_amdgcn_mfma_f32_16x16x32_bf16(whh[kt][1], blo, aC1, 0, 0, 0);
            }
        }

        // x term (feature mask: quad-uniform; inactive quads contribute 0)
        bf16x8 xhi = {0,0,0,0,0,0,0,0}, xlo = {0,0,0,0,0,0,0,0};
        if (q * 8 < NF) {
            unsigned p0 = cvtpk(cxa[0], cxa[1]), p1 = cvtpk(cxa[2], cxa[3]);
            unsigned p2 = cvtpk(cxb[0], cxb[1]), p3 = cvtpk(cxb[2], cxb[3]);
            float g0 = __uint_as_float(p0 << 16), g1 = __uint_as_float(p0 & 0xffff0000u);
            float g2 = __uint_as_float(p1 << 16), g3 = __uint_as_float(p1 & 0xffff0000u);
            float g4 = __uint_as_float(p2 << 16), g5 = __uint_as_float(p2 & 0xffff0000u);
            float g6 = __uint_as_float(p3 << 16), g7 = __uint_as_float(p3 & 0xffff0000u);
            unsigned l0 = cvtpk(cxa[0] - g0, cxa[1] - g1);
            unsigned l1 = cvtpk(cxa[2] - g2, cxa[3] - g3);
            unsigned l2 = cvtpk(cxb[0] - g4, cxb[1] - g5);
            unsigned l3 = cvtpk(cxb[2] - g6, cxb[3] - g7);
            union { i32x4 i; bf16x8 h; } uh, ul;
            uh.i = (i32x4){(int)p0, (int)p1, (int)p2, (int)p3};
            ul.i = (i32x4){(int)l0, (int)l1, (int)l2, (int)l3};
            xhi = uh.h; xlo = ul.h;
        }
        aA0 = __builtin_amdgcn_mfma_f32_16x16x32_bf16(wxh[0], xhi, aA0, 0, 0, 0);
        aB0 = __builtin_amdgcn_mfma_f32_16x16x32_bf16(wxl[0], xhi, aB0, 0, 0, 0);
        aC0 = __builtin_amdgcn_mfma_f32_16x16x32_bf16(wxh[0], xlo, aC0, 0, 0, 0);
        if (S == 2 || (S == 1 && m1act)) {
            aA1 = __builtin_amdgcn_mfma_f32_16x16x32_bf16(wxh[1], xhi, aA1, 0, 0, 0);
            aB1 = __builtin_amdgcn_mfma_f32_16x16x32_bf16(wxl[1], xhi, aB1, 0, 0, 0);
            aC1 = __builtin_amdgcn_mfma_f32_16x16x32_bf16(wxh[1], xlo, aC1, 0, 0, 0);
        }

        // epilogue: merge, tanh, pack hi/lo, write (lanes r<8 only; rows 0..7)
        if (r < 8) {
            {
                const f32x4 s = aA0 + aB0 + aC0;
                const float t0 = fast_tanh(s[0]), t1 = fast_tanh(s[1]);
                const float t2 = fast_tanh(s[2]), t3 = fast_tanh(s[3]);
                unsigned hp0 = cvtpk(t0, t1), hp1 = cvtpk(t2, t3);
                float g0 = __uint_as_float(hp0 << 16), g1 = __uint_as_float(hp0 & 0xffff0000u);
                float g2 = __uint_as_float(hp1 << 16), g3 = __uint_as_float(hp1 & 0xffff0000u);
                unsigned lp0 = cvtpk(t0 - g0, t1 - g1), lp1 = cvtpk(t2 - g2, t3 - g3);
                const int off = rb * PADK + (w << 4) + q * 4;
                *(i32x2*)&nh_hi[off] = (i32x2){(int)hp0, (int)hp1};
                *(i32x2*)&nh_lo[off] = (i32x2){(int)lp0, (int)lp1};
            }
            const int off1 = rb * PADK + ((8 + w) << 4) + q * 4;
            if (m1act) {
                const f32x4 s = aA1 + aB1 + aC1;
                const float t0 = fast_tanh(s[0]), t1 = fast_tanh(s[1]);
                const float t2 = fast_tanh(s[2]), t3 = fast_tanh(s[3]);
                unsigned hp0 = cvtpk(t0, t1), hp1 = cvtpk(t2, t3);
                float g0 = __uint_as_float(hp0 << 16), g1 = __uint_as_float(hp0 & 0xffff0000u);
                float g2 = __uint_as_float(hp1 << 16), g3 = __uint_as_float(hp1 & 0xffff0000u);
                unsigned lp0 = cvtpk(t0 - g0, t1 - g1), lp1 = cvtpk(t2 - g2, t3 - g3);
                *(i32x2*)&nh_hi[off1] = (i32x2){(int)hp0, (int)hp1};
                *(i32x2*)&nh_lo[off1] = (i32x2){(int)lp0, (int)lp1};
            } else {
                // clockwork carry: copy stale tile 8+w forward
                *(i32x2*)&nh_hi[off1] = *(const i32x2*)&rh_hi[off1];
                *(i32x2*)&nh_lo[off1] = *(const i32x2*)&rh_lo[off1];
            }
        }
        __syncthreads();
        cur ^= 1;
        cxa = pxa; cxb = pxb;
    };

    for (int j = 0; j < TT; j += 4) {
        body(j + 0, IC<0>{});   // jp odd             -> NC=128
        body(j + 1, IC<1>{});   // jp%2==0, jp%4!=0   -> NC=192
        body(j + 2, IC<0>{});   // jp odd             -> NC=128
        body(j + 3, IC<2>{});   // jp%4==0            -> NC=256
    }
    // final h in buffer 0

    // ---- rebuild h fp32, transposed [k][row] (reuse scratch) ----
    float* hT = scratch;
    for (int i = t; i < DH1 * ROWS8; i += 512) {
        const int row = i & 7, k = i >> 3;
        hT[k * ROWS8 + row] = bf2f(hb_hi[0][row * PADK + k]) + bf2f(hb_lo[0][row * PADK + k]);
    }
    __syncthreads();

    // ---- head: hid = relu(h @ W1 + b1); y = hid @ W2 + b2 ----
    // thread t -> col t of DH2; 8 batch rows each.
    const float* W1_g = W1 + (size_t)y * DH1 * DH2;
    float a0[8];
    #pragma unroll
    for (int m = 0; m < 8; ++m) a0[m] = 0.f;
    for (int k = 0; k < DH1; ++k) {
        const float wv = W1_g[(size_t)k * DH2 + t];
        const f32x4 hA = *(const f32x4*)&hT[k * ROWS8];
        const f32x4 hB = *(const f32x4*)&hT[k * ROWS8 + 4];
        a0[0] += hA[0] * wv; a0[1] += hA[1] * wv;
        a0[2] += hA[2] * wv; a0[3] += hA[3] * wv;
        a0[4] += hB[0] * wv; a0[5] += hB[1] * wv;
        a0[6] += hB[2] * wv; a0[7] += hB[3] * wv;
    }
    {
        const float b1v = b1[y * DH2 + t];
        const float w2v = W2[y * DH2 + t];
        float p[8];
        #pragma unroll
        for (int m = 0; m < 8; ++m)
            p[m] = fmaxf(a0[m] + b1v, 0.f) * w2v;
        #pragma unroll
        for (int m = 0; m < 8; ++m) {
            float v = p[m];
            for (int off = 32; off > 0; off >>= 1) v += __shfl_down(v, off);
            if (lane == 0) red[w][m] = v;
        }
    }
    __syncthreads();
    if (t < ROWS8) {
        float s = b2[y];
        #pragma unroll
        for (int ww = 0; ww < 8; ++ww) s += red[ww][t];
        out[(size_t)(b0 + t) * NY + y] = s;
    }
}

extern "C" void kernel_launch(void* const* d_in, const int* in_sizes, int n_in,
                              void* d_out, int out_size, void* d_ws, size_t ws_size,
                              hipStream_t stream) {
    const float* x   = (const float*)d_in[0];
    const float* w_x = (const float*)d_in[1];
    const float* w_h = (const float*)d_in[2];
    const float* b   = (const float*)d_in[3];
    const float* W1  = (const float*)d_in[4];
    const float* b1  = (const float*)d_in[5];
    const float* W2  = (const float*)d_in[6];
    const float* b2  = (const float*)d_in[7];
    float* out = (float*)d_out;

    dim3 grid(256), block(512);
    hipLaunchKernelGGL(cwrnn_mfma4, grid, block, 0, stream,
                       x, w_x, w_h, b, W1, b1, W2, b2, out);
}

// Round 7
// 226.040 us; speedup vs baseline: 4.9768x; 1.0558x over previous
//
#include <hip/hip_runtime.h>
#include <math.h>

// Clockwork RNN, B=512 T=192 DX=32 DH1=256 DH2=512 DY=4
// R6 = R5 with the bias double-count fixed: in the packed hi|lo B scheme the
// epilogue sums accumulator lane-halves (s = v + shfl_xor(v,8)), so bias must
// be initialized in ONLY ONE half (r<8). R5 had it in both -> 2*bias -> 2.7e-2.
//
// Structure: packed hi|lo B-fragment -> 2 MFMA chains, halved h LDS reads:
//   B cols 0-7 = h_hi rows 0-7, cols 8-15 = h_lo rows 0-7:
//     A=W_hi MFMA -> D[c]=Whi*hhi | Whi*hlo ; A=W_lo -> Wlo*hhi | Wlo*hlo
//   merge s = v + shfl_xor(v,8) = (Whi+Wlo)*(hhi+hlo)  (exact 4-term)
// x pre-converted to bf16 hi/lo in LDS per 64-step chunk.
// 256 blocks x 512 thr (2 waves/SIMD, all 256 CUs), 1 barrier/step.

#define TT    192
#define DXX   32
#define DH1   256
#define DH2   512
#define NY    4
#define ROWS8 8
#define PADK  264
#define CHUNK 64

typedef __attribute__((ext_vector_type(8))) short bf16x8;
typedef __attribute__((ext_vector_type(4))) float f32x4;
typedef __attribute__((ext_vector_type(2))) int   i32x2;
typedef __attribute__((ext_vector_type(4))) int   i32x4;

template<int N> struct IC { static constexpr int v = N; };

__device__ __forceinline__ short f2bf(float f) {
    unsigned u = __float_as_uint(f);
    unsigned rr = (u + 0x7FFFu + ((u >> 16) & 1u)) >> 16;
    return (short)rr;
}
__device__ __forceinline__ float bf2f(short h) {
    return __uint_as_float(((unsigned)(unsigned short)h) << 16);
}
__device__ __forceinline__ unsigned cvtpk(float a, float b) {
    unsigned d;
    asm("v_cvt_pk_bf16_f32 %0, %1, %2" : "=v"(d) : "v"(a), "v"(b));
    return d;   // lo16 = bf16(a), hi16 = bf16(b)
}
__device__ __forceinline__ float fast_tanh(float v) {
    float t = __builtin_amdgcn_exp2f(v * 2.885390081777927f);
    return fmaf(-2.f, __builtin_amdgcn_rcpf(t + 1.f), 1.f);
}

__global__ __launch_bounds__(512, 2) void cwrnn_mfma6(
    const float* __restrict__ x,     // [B,T,DX]
    const float* __restrict__ w_x,   // [DY,DX,DH1]
    const float* __restrict__ w_h,   // [DY,DH1,DH1]
    const float* __restrict__ bias,  // [DY,DH1]
    const float* __restrict__ W1,    // [DY,DH1,DH2]
    const float* __restrict__ b1,    // [DY,DH2]
    const float* __restrict__ W2,    // [DY,DH2]
    const float* __restrict__ b2,    // [DY]
    float* __restrict__ out)         // [B,DY]
{
    __shared__ short hb_hi[2][ROWS8 * PADK];   // h bf16 hi, [buf][row][k]
    __shared__ short hb_lo[2][ROWS8 * PADK];   // h bf16 lo
    __shared__ float red[8][ROWS8];
    __shared__ union Pool {
        float scratch[DXX * DH1];              // setup staging / final hT
        short xpk[2][CHUNK * 32 * 8];          // x bf16 [hi/lo][j][q][rb] 16B slots
    } pool;
    __shared__ __align__(16) int xzero[4];     // zero B-slot for feature mask

    const int t    = threadIdx.x;
    const int lane = t & 63;
    const int w    = t >> 6;        // wave 0..7; tiles {w, 8+w}
    const int r    = lane & 15;
    const int rb   = r & 7;
    const int q    = lane >> 4;
    const int y    = blockIdx.x & 3;
    const int b0   = (blockIdx.x >> 2) * ROWS8;

    const float* wx_g = w_x + (size_t)y * DXX * DH1;
    const float* wh_g = w_h + (size_t)y * DH1 * DH1;

    for (int i = t; i < ROWS8 * PADK; i += 512) { hb_hi[0][i] = 0; hb_lo[0][i] = 0; }
    if (t < 4) xzero[t] = 0;

    // ---- w_x fragments: wave w -> tiles {w, 8+w} ----
    bf16x8 wxh[2], wxl[2];
    for (int i = t * 4; i < DXX * DH1; i += 2048)
        *(f32x4*)&pool.scratch[i] = *(const f32x4*)&wx_g[i];
    __syncthreads();
    #pragma unroll
    for (int m = 0; m < 2; ++m) {
        bf16x8 vh, vl;
        #pragma unroll
        for (int jj = 0; jj < 8; ++jj) {
            float v = pool.scratch[(q * 8 + jj) * DH1 + ((m * 8 + w) << 4) + r];
            short hi = f2bf(v);
            vh[jj] = hi; vl[jj] = f2bf(v - bf2f(hi));
        }
        wxh[m] = vh; wxl[m] = vl;
    }
    __syncthreads();

    // ---- w_h fragments: 8 ktiles x 2 mtiles, hi/lo. FULLY UNROLLED
    // (runtime index -> scratch demotion; R2 lesson). ----
    bf16x8 whh[8][2], whl[8][2];
    #pragma unroll
    for (int kt = 0; kt < 8; ++kt) {
        for (int i = t * 4; i < 32 * DH1; i += 2048)
            *(f32x4*)&pool.scratch[i] = *(const f32x4*)&wh_g[kt * 32 * DH1 + i];
        __syncthreads();
        #pragma unroll
        for (int m = 0; m < 2; ++m) {
            bf16x8 vh, vl;
            #pragma unroll
            for (int jj = 0; jj < 8; ++jj) {
                float v = pool.scratch[(q * 8 + jj) * DH1 + ((m * 8 + w) << 4) + r];
                short hi = f2bf(v);
                vh[jj] = hi; vl[jj] = f2bf(v - bf2f(hi));
            }
            whh[kt][m] = vh; whl[kt][m] = vl;
        }
        __syncthreads();
    }

    // bias in the r<8 half ONLY (the shfl_xor(.,8) merge sums both halves;
    // R5 bug: bias in both halves -> 2*bias)
    f32x4 bias4[2];
    #pragma unroll
    for (int m = 0; m < 2; ++m)
        #pragma unroll
        for (int rr = 0; rr < 4; ++rr)
            bias4[m][rr] = (r < 8) ? bias[y * DH1 + ((m * 8 + w) << 4) + q * 4 + rr]
                                   : 0.f;

    // ---- per-lane LDS pointers ----
    // B-fragment read: lanes r<8 -> h_hi[row rb], lanes r>=8 -> h_lo[row rb]
    const short* hrd[2] = {
        (r < 8 ? &hb_hi[0][rb * PADK] : &hb_lo[0][rb * PADK]) + q * 8,
        (r < 8 ? &hb_hi[1][rb * PADK] : &hb_lo[1][rb * PADK]) + q * 8
    };
    // write bases (row rb, tile w, k-sub q*4); tile1 at +128 shorts
    short* hw_hi[2] = { &hb_hi[0][rb * PADK + w * 16 + q * 4],
                        &hb_hi[1][rb * PADK + w * 16 + q * 4] };
    short* hw_lo[2] = { &hb_lo[0][rb * PADK + w * 16 + q * 4],
                        &hb_lo[1][rb * PADK + w * 16 + q * 4] };
    const short* xsel = (r < 8 ? pool.xpk[0] : pool.xpk[1]) + (q * 8 + rb) * 8;
    const short* xz   = (const short*)xzero;

    // ---- x chunk pre-pass: convert 64 steps of x to bf16 hi/lo in LDS ----
    auto xconv = [&](int j0) {
        const int rbz = t >> 6, jz = t & 63;   // wave -> row, lane -> step
        const float* xp = x + ((size_t)(b0 + rbz) * TT + (j0 + jz)) * DXX;
        #pragma unroll
        for (int qq = 0; qq < 4; ++qq) {
            const f32x4 a = *(const f32x4*)(xp + qq * 8);
            const f32x4 b = *(const f32x4*)(xp + qq * 8 + 4);
            unsigned p0 = cvtpk(a[0], a[1]), p1 = cvtpk(a[2], a[3]);
            unsigned p2 = cvtpk(b[0], b[1]), p3 = cvtpk(b[2], b[3]);
            float g0 = __uint_as_float(p0 << 16), g1 = __uint_as_float(p0 & 0xffff0000u);
            float g2 = __uint_as_float(p1 << 16), g3 = __uint_as_float(p1 & 0xffff0000u);
            float g4 = __uint_as_float(p2 << 16), g5 = __uint_as_float(p2 & 0xffff0000u);
            float g6 = __uint_as_float(p3 << 16), g7 = __uint_as_float(p3 & 0xffff0000u);
            unsigned l0 = cvtpk(a[0] - g0, a[1] - g1), l1 = cvtpk(a[2] - g2, a[3] - g3);
            unsigned l2 = cvtpk(b[0] - g4, b[1] - g5), l3 = cvtpk(b[2] - g6, b[3] - g7);
            const int slot = (jz * 4 + qq) * 8 + rbz;
            *(i32x4*)&pool.xpk[0][slot * 8] = (i32x4){(int)p0, (int)p1, (int)p2, (int)p3};
            *(i32x4*)&pool.xpk[1][slot * 8] = (i32x4){(int)l0, (int)l1, (int)l2, (int)l3};
        }
    };

    // ---- one recurrence step ----
    auto body = [&](int jmod, auto SC, int cur) {
        constexpr int S  = SC.v;                       // 0:NC=128 1:192 2:256
        constexpr int NF = (S == 0) ? 16 : (S == 1) ? 24 : 32;
        const bool m1act = (S == 2) || (S == 1 && w < 4);

        const short* hp = hrd[cur];

        // x B-fragment (hi|lo packed by lane half); feature-mask via zero slot
        const short* xp;
        if constexpr (NF == 32) xp = xsel + jmod * 256;
        else                    xp = (q * 8 < NF) ? (xsel + jmod * 256) : xz;
        const bf16x8 xf = *(const bf16x8*)xp;

        f32x4 aA0 = bias4[0], aB0 = {0,0,0,0};
        f32x4 aA1 = bias4[1], aB1 = {0,0,0,0};

        #pragma unroll
        for (int kt = 0; kt < 8; ++kt) {
            const bf16x8 hv = *(const bf16x8*)(hp + kt * 32);
            aA0 = __builtin_amdgcn_mfma_f32_16x16x32_bf16(whh[kt][0], hv, aA0, 0, 0, 0);
            aB0 = __builtin_amdgcn_mfma_f32_16x16x32_bf16(whl[kt][0], hv, aB0, 0, 0, 0);
            if (S == 2 || (S == 1 && m1act)) {
                aA1 = __builtin_amdgcn_mfma_f32_16x16x32_bf16(whh[kt][1], hv, aA1, 0, 0, 0);
                aB1 = __builtin_amdgcn_mfma_f32_16x16x32_bf16(whl[kt][1], hv, aB1, 0, 0, 0);
            }
        }
        aA0 = __builtin_amdgcn_mfma_f32_16x16x32_bf16(wxh[0], xf, aA0, 0, 0, 0);
        aB0 = __builtin_amdgcn_mfma_f32_16x16x32_bf16(wxl[0], xf, aB0, 0, 0, 0);
        if (S == 2 || (S == 1 && m1act)) {
            aA1 = __builtin_amdgcn_mfma_f32_16x16x32_bf16(wxh[1], xf, aA1, 0, 0, 0);
            aB1 = __builtin_amdgcn_mfma_f32_16x16x32_bf16(wxl[1], xf, aB1, 0, 0, 0);
        }

        // ---- epilogue tile 0: merge halves, tanh, pack, write ----
        {
            const f32x4 v = aA0 + aB0;
            const float s0 = v[0] + __shfl_xor(v[0], 8);
            const float s1 = v[1] + __shfl_xor(v[1], 8);
            const float s2 = v[2] + __shfl_xor(v[2], 8);
            const float s3 = v[3] + __shfl_xor(v[3], 8);
            const float t0 = fast_tanh(s0), t1 = fast_tanh(s1);
            const float t2 = fast_tanh(s2), t3 = fast_tanh(s3);
            unsigned hp0 = cvtpk(t0, t1), hp1 = cvtpk(t2, t3);
            float g0 = __uint_as_float(hp0 << 16), g1 = __uint_as_float(hp0 & 0xffff0000u);
            float g2 = __uint_as_float(hp1 << 16), g3 = __uint_as_float(hp1 & 0xffff0000u);
            unsigned lp0 = cvtpk(t0 - g0, t1 - g1), lp1 = cvtpk(t2 - g2, t3 - g3);
            if (r < 8) {
                *(i32x2*)(hw_hi[cur ^ 1]) = (i32x2){(int)hp0, (int)hp1};
                *(i32x2*)(hw_lo[cur ^ 1]) = (i32x2){(int)lp0, (int)lp1};
            }
        }
        // ---- epilogue tile 1 (or clockwork carry) ----
        if (m1act) {
            const f32x4 v = aA1 + aB1;
            const float s0 = v[0] + __shfl_xor(v[0], 8);
            const float s1 = v[1] + __shfl_xor(v[1], 8);
            const float s2 = v[2] + __shfl_xor(v[2], 8);
            const float s3 = v[3] + __shfl_xor(v[3], 8);
            const float t0 = fast_tanh(s0), t1 = fast_tanh(s1);
            const float t2 = fast_tanh(s2), t3 = fast_tanh(s3);
            unsigned hp0 = cvtpk(t0, t1), hp1 = cvtpk(t2, t3);
            float g0 = __uint_as_float(hp0 << 16), g1 = __uint_as_float(hp0 & 0xffff0000u);
            float g2 = __uint_as_float(hp1 << 16), g3 = __uint_as_float(hp1 & 0xffff0000u);
            unsigned lp0 = cvtpk(t0 - g0, t1 - g1), lp1 = cvtpk(t2 - g2, t3 - g3);
            if (r < 8) {
                *(i32x2*)(hw_hi[cur ^ 1] + 128) = (i32x2){(int)hp0, (int)hp1};
                *(i32x2*)(hw_lo[cur ^ 1] + 128) = (i32x2){(int)lp0, (int)lp1};
            }
        } else {
            if (r < 8) {
                *(i32x2*)(hw_hi[cur ^ 1] + 128) = *(const i32x2*)(hw_hi[cur] + 128);
                *(i32x2*)(hw_lo[cur ^ 1] + 128) = *(const i32x2*)(hw_lo[cur] + 128);
            }
        }
        __syncthreads();
    };

    // ---- main loop: 3 chunks of 64 steps ----
    for (int j = 0; j < TT; j += 4) {
        const int jm = j & (CHUNK - 1);
        if (jm == 0) { xconv(j); __syncthreads(); }
        body(jm + 0, IC<0>{}, 0);   // jp odd           -> NC=128
        body(jm + 1, IC<1>{}, 1);   // jp%2==0, %4!=0   -> NC=192
        body(jm + 2, IC<0>{}, 0);   // jp odd           -> NC=128
        body(jm + 3, IC<2>{}, 1);   // jp%4==0          -> NC=256
    }
    // final h in buffer 0

    // ---- rebuild h fp32, transposed [k][row] ----
    float* hT = pool.scratch;
    for (int i = t; i < DH1 * ROWS8; i += 512) {
        const int row = i & 7, k = i >> 3;
        hT[k * ROWS8 + row] = bf2f(hb_hi[0][row * PADK + k]) + bf2f(hb_lo[0][row * PADK + k]);
    }
    __syncthreads();

    // ---- head: hid = relu(h @ W1 + b1); y = hid @ W2 + b2 ----
    const float* W1_g = W1 + (size_t)y * DH1 * DH2;
    float a0[8];
    #pragma unroll
    for (int m = 0; m < 8; ++m) a0[m] = 0.f;
    for (int k = 0; k < DH1; ++k) {
        const float wv = W1_g[(size_t)k * DH2 + t];
        const f32x4 hA = *(const f32x4*)&hT[k * ROWS8];
        const f32x4 hB = *(const f32x4*)&hT[k * ROWS8 + 4];
        a0[0] += hA[0] * wv; a0[1] += hA[1] * wv;
        a0[2] += hA[2] * wv; a0[3] += hA[3] * wv;
        a0[4] += hB[0] * wv; a0[5] += hB[1] * wv;
        a0[6] += hB[2] * wv; a0[7] += hB[3] * wv;
    }
    {
        const float b1v = b1[y * DH2 + t];
        const float w2v = W2[y * DH2 + t];
        float p[8];
        #pragma unroll
        for (int m = 0; m < 8; ++m)
            p[m] = fmaxf(a0[m] + b1v, 0.f) * w2v;
        #pragma unroll
        for (int m = 0; m < 8; ++m) {
            float v = p[m];
            for (int off = 32; off > 0; off >>= 1) v += __shfl_down(v, off);
            if (lane == 0) red[w][m] = v;
        }
    }
    __syncthreads();
    if (t < ROWS8) {
        float s = b2[y];
        #pragma unroll
        for (int ww = 0; ww < 8; ++ww) s += red[ww][t];
        out[(size_t)(b0 + t) * NY + y] = s;
    }
}

extern "C" void kernel_launch(void* const* d_in, const int* in_sizes, int n_in,
                              void* d_out, int out_size, void* d_ws, size_t ws_size,
                              hipStream_t stream) {
    const float* x   = (const float*)d_in[0];
    const float* w_x = (const float*)d_in[1];
    const float* w_h = (const float*)d_in[2];
    const float* b   = (const float*)d_in[3];
    const float* W1  = (const float*)d_in[4];
    const float* b1  = (const float*)d_in[5];
    const float* W2  = (const float*)d_in[6];
    const float* b2  = (const float*)d_in[7];
    float* out = (float*)d_out;

    dim3 grid(256), block(512);
    hipLaunchKernelGGL(cwrnn_mfma6, grid, block, 0, stream,
                       x, w_x, w_h, b, W1, b1, W2, b2, out);
}

// Round 8
// 175.177 us; speedup vs baseline: 6.4218x; 1.2904x over previous
//
#include <hip/hip_runtime.h>
#include <math.h>

// Clockwork RNN, B=512 T=192 DX=32 DH1=256 DH2=512 DY=4
// R7: cut the LDS pipe (R6's real bottleneck) ~2.5x:
//  - h state: SINGLE fp16 array (tanh-bounded, rel err 4.9e-4). B-fragment
//    lanes r and r+8 read the SAME address (broadcast); both D halves compute
//    identical values -> NO cross-lane merge (R6's 8 ds_bpermute/step gone),
//    h reads effectively halve, h writes halve.
//  - W register-resident as fp16 hi + lo*2^12 (subnormal-safe); merge
//    intra-lane: s = aA + aB * 2^-12. Product error ~exact; only h-quant
//    (random ~7e-5/step) accumulates -> margin vs 4.2e-3 threshold.
//  - x: register prefetch + per-step pkrtz pack (xpk LDS buffer deleted;
//    its reads were 4-way bank-conflicted).
//  - h repack: RNE scalar cvt (not RTZ) to avoid systematic drift.
// 256 blocks x 512 thr (8 waves, 2/SIMD), 1 barrier/step, W fully unrolled
// into registers (R2 scratch-demotion lesson).

#define TT    192
#define DXX   32
#define DH1   256
#define DH2   512
#define NY    4
#define ROWS8 8
#define PADK  264   // row stride in fp16 elems; 528B = 16 mod 128 -> rows hit
                    // distinct 16B bank windows

typedef _Float16 f16x8 __attribute__((ext_vector_type(8)));
typedef __attribute__((ext_vector_type(4))) float f32x4;
typedef __attribute__((ext_vector_type(2))) int   i32x2;
typedef __attribute__((ext_vector_type(4))) int   i32x4;

template<int N> struct IC { static constexpr int v = N; };

__device__ __forceinline__ unsigned pkrtz(float a, float b) {
    unsigned d;
    asm("v_cvt_pkrtz_f16_f32 %0, %1, %2" : "=v"(d) : "v"(a), "v"(b));
    return d;   // lo16 = f16(a), hi16 = f16(b), round-to-zero (x input only)
}
__device__ __forceinline__ unsigned short f16bits(_Float16 h) {
    union { _Float16 f; unsigned short u; } c; c.f = h; return c.u;
}
__device__ __forceinline__ float fast_tanh(float v) {
    float t = __builtin_amdgcn_exp2f(v * 2.885390081777927f);
    return fmaf(-2.f, __builtin_amdgcn_rcpf(t + 1.f), 1.f);
}

__global__ __launch_bounds__(512, 2) void cwrnn_mfma7(
    const float* __restrict__ x,     // [B,T,DX]
    const float* __restrict__ w_x,   // [DY,DX,DH1]
    const float* __restrict__ w_h,   // [DY,DH1,DH1]
    const float* __restrict__ bias,  // [DY,DH1]
    const float* __restrict__ W1,    // [DY,DH1,DH2]
    const float* __restrict__ b1,    // [DY,DH2]
    const float* __restrict__ W2,    // [DY,DH2]
    const float* __restrict__ b2,    // [DY]
    float* __restrict__ out)         // [B,DY]
{
    __shared__ _Float16 hb[2][ROWS8 * PADK];   // h fp16, [buf][row][k]
    __shared__ float red[8][ROWS8];
    __shared__ float scratch[DXX * DH1];       // 32KB staging; reused as hT

    const int t    = threadIdx.x;
    const int lane = t & 63;
    const int w    = t >> 6;        // wave 0..7; tiles {w, 8+w}
    const int r    = lane & 15;
    const int rb   = r & 7;         // batch row (r and r+8 duplicate)
    const int q    = lane >> 4;
    const int y    = blockIdx.x & 3;
    const int b0   = (blockIdx.x >> 2) * ROWS8;

    const float* wx_g = w_x + (size_t)y * DXX * DH1;
    const float* wh_g = w_h + (size_t)y * DH1 * DH1;

    for (int i = t; i < ROWS8 * PADK; i += 512) hb[0][i] = (_Float16)0.f;

    // ---- w_x fragments: wave w -> tiles {w, 8+w}; fp16 hi + lo*2^12 ----
    f16x8 wxh[2], wxl[2];
    for (int i = t * 4; i < DXX * DH1; i += 2048)
        *(f32x4*)&scratch[i] = *(const f32x4*)&wx_g[i];
    __syncthreads();
    #pragma unroll
    for (int m = 0; m < 2; ++m) {
        f16x8 vh, vl;
        #pragma unroll
        for (int jj = 0; jj < 8; ++jj) {
            float v = scratch[(q * 8 + jj) * DH1 + ((m * 8 + w) << 4) + r];
            _Float16 hi = (_Float16)v;
            vh[jj] = hi;
            vl[jj] = (_Float16)((v - (float)hi) * 4096.f);
        }
        wxh[m] = vh; wxl[m] = vl;
    }
    __syncthreads();

    // ---- w_h fragments: 8 ktiles x 2 mtiles, fp16 hi/lo. FULLY UNROLLED
    // (runtime index -> scratch demotion; R2 lesson). ----
    f16x8 whh[8][2], whl[8][2];
    #pragma unroll
    for (int kt = 0; kt < 8; ++kt) {
        for (int i = t * 4; i < 32 * DH1; i += 2048)
            *(f32x4*)&scratch[i] = *(const f32x4*)&wh_g[kt * 32 * DH1 + i];
        __syncthreads();
        #pragma unroll
        for (int m = 0; m < 2; ++m) {
            f16x8 vh, vl;
            #pragma unroll
            for (int jj = 0; jj < 8; ++jj) {
                float v = scratch[(q * 8 + jj) * DH1 + ((m * 8 + w) << 4) + r];
                _Float16 hi = (_Float16)v;
                vh[jj] = hi;
                vl[jj] = (_Float16)((v - (float)hi) * 4096.f);
            }
            whh[kt][m] = vh; whl[kt][m] = vl;
        }
        __syncthreads();
    }

    // bias in ALL lanes (no cross-lane merge in this scheme)
    f32x4 bias4[2];
    #pragma unroll
    for (int m = 0; m < 2; ++m)
        #pragma unroll
        for (int rr = 0; rr < 4; ++rr)
            bias4[m][rr] = bias[y * DH1 + ((m * 8 + w) << 4) + q * 4 + rr];

    // ---- per-lane LDS pointers ----
    const _Float16* hrd[2] = { &hb[0][rb * PADK] + q * 8,
                               &hb[1][rb * PADK] + q * 8 };
    _Float16* hwr[2] = { &hb[0][rb * PADK + w * 16 + q * 4],
                         &hb[1][rb * PADK + w * 16 + q * 4] };

    const float* xrow = x + (size_t)(b0 + rb) * TT * DXX + q * 8;
    f32x4 cxa = *(const f32x4*)&xrow[0];
    f32x4 cxb = *(const f32x4*)&xrow[4];

    // ---- one recurrence step ----
    auto body = [&](int j, auto SC, int cur) {
        constexpr int S  = SC.v;                       // 0:NC=128 1:192 2:256
        constexpr int NF = (S == 0) ? 16 : (S == 1) ? 24 : 32;
        const bool m1act = (S == 2) || (S == 1 && w < 4);

        // prefetch next step's x
        const int jn = (j + 1 < TT) ? j + 1 : j;
        const f32x4 pxa = *(const f32x4*)&xrow[jn * DXX];
        const f32x4 pxb = *(const f32x4*)&xrow[jn * DXX + 4];

        // x B-fragment, fp16 (quad-uniform feature mask)
        f16x8 xf;
        if (q * 8 < NF) {
            union { i32x4 i; f16x8 h; } ux;
            ux.i = (i32x4){ (int)pkrtz(cxa[0], cxa[1]), (int)pkrtz(cxa[2], cxa[3]),
                            (int)pkrtz(cxb[0], cxb[1]), (int)pkrtz(cxb[2], cxb[3]) };
            xf = ux.h;
        } else {
            xf = (f16x8)(_Float16)0.f;
        }

        const _Float16* hp = hrd[cur];

        f32x4 aA0 = bias4[0], aB0 = {0,0,0,0};
        f32x4 aA1 = bias4[1], aB1 = {0,0,0,0};

        #pragma unroll
        for (int kt = 0; kt < 8; ++kt) {
            const f16x8 hv = *(const f16x8*)(hp + kt * 32);
            aA0 = __builtin_amdgcn_mfma_f32_16x16x32_f16(whh[kt][0], hv, aA0, 0, 0, 0);
            aB0 = __builtin_amdgcn_mfma_f32_16x16x32_f16(whl[kt][0], hv, aB0, 0, 0, 0);
            if (S == 2 || (S == 1 && m1act)) {
                aA1 = __builtin_amdgcn_mfma_f32_16x16x32_f16(whh[kt][1], hv, aA1, 0, 0, 0);
                aB1 = __builtin_amdgcn_mfma_f32_16x16x32_f16(whl[kt][1], hv, aB1, 0, 0, 0);
            }
        }
        aA0 = __builtin_amdgcn_mfma_f32_16x16x32_f16(wxh[0], xf, aA0, 0, 0, 0);
        aB0 = __builtin_amdgcn_mfma_f32_16x16x32_f16(wxl[0], xf, aB0, 0, 0, 0);
        if (S == 2 || (S == 1 && m1act)) {
            aA1 = __builtin_amdgcn_mfma_f32_16x16x32_f16(wxh[1], xf, aA1, 0, 0, 0);
            aB1 = __builtin_amdgcn_mfma_f32_16x16x32_f16(wxl[1], xf, aB1, 0, 0, 0);
        }

        // ---- epilogue tile 0: s = aA + aB*2^-12, tanh, RNE pack, write ----
        {
            const float s0 = fmaf(aB0[0], 2.44140625e-4f, aA0[0]);
            const float s1 = fmaf(aB0[1], 2.44140625e-4f, aA0[1]);
            const float s2 = fmaf(aB0[2], 2.44140625e-4f, aA0[2]);
            const float s3 = fmaf(aB0[3], 2.44140625e-4f, aA0[3]);
            const unsigned short h0 = f16bits((_Float16)fast_tanh(s0));
            const unsigned short h1 = f16bits((_Float16)fast_tanh(s1));
            const unsigned short h2 = f16bits((_Float16)fast_tanh(s2));
            const unsigned short h3 = f16bits((_Float16)fast_tanh(s3));
            if (r < 8) {
                *(i32x2*)(hwr[cur ^ 1]) =
                    (i32x2){ (int)(h0 | ((unsigned)h1 << 16)),
                             (int)(h2 | ((unsigned)h3 << 16)) };
            }
        }
        // ---- epilogue tile 1 (or clockwork carry) ----
        if (m1act) {
            const float s0 = fmaf(aB1[0], 2.44140625e-4f, aA1[0]);
            const float s1 = fmaf(aB1[1], 2.44140625e-4f, aA1[1]);
            const float s2 = fmaf(aB1[2], 2.44140625e-4f, aA1[2]);
            const float s3 = fmaf(aB1[3], 2.44140625e-4f, aA1[3]);
            const unsigned short h0 = f16bits((_Float16)fast_tanh(s0));
            const unsigned short h1 = f16bits((_Float16)fast_tanh(s1));
            const unsigned short h2 = f16bits((_Float16)fast_tanh(s2));
            const unsigned short h3 = f16bits((_Float16)fast_tanh(s3));
            if (r < 8) {
                *(i32x2*)(hwr[cur ^ 1] + 128) =
                    (i32x2){ (int)(h0 | ((unsigned)h1 << 16)),
                             (int)(h2 | ((unsigned)h3 << 16)) };
            }
        } else {
            if (r < 8)
                *(i32x2*)(hwr[cur ^ 1] + 128) = *(const i32x2*)(hwr[cur] + 128);
        }
        __syncthreads();
        cxa = pxa; cxb = pxb;
    };

    // ---- main loop ----
    for (int j = 0; j < TT; j += 4) {
        body(j + 0, IC<0>{}, 0);   // jp odd           -> NC=128
        body(j + 1, IC<1>{}, 1);   // jp%2==0, %4!=0   -> NC=192
        body(j + 2, IC<0>{}, 0);   // jp odd           -> NC=128
        body(j + 3, IC<2>{}, 1);   // jp%4==0          -> NC=256
    }
    // final h in buffer 0

    // ---- rebuild h fp32, transposed [k][row] ----
    float* hT = scratch;
    for (int i = t; i < DH1 * ROWS8; i += 512) {
        const int row = i & 7, k = i >> 3;
        hT[k * ROWS8 + row] = (float)hb[0][row * PADK + k];
    }
    __syncthreads();

    // ---- head: hid = relu(h @ W1 + b1); y = hid @ W2 + b2 ----
    const float* W1_g = W1 + (size_t)y * DH1 * DH2;
    float a0[8];
    #pragma unroll
    for (int m = 0; m < 8; ++m) a0[m] = 0.f;
    for (int k = 0; k < DH1; ++k) {
        const float wv = W1_g[(size_t)k * DH2 + t];
        const f32x4 hA = *(const f32x4*)&hT[k * ROWS8];
        const f32x4 hB = *(const f32x4*)&hT[k * ROWS8 + 4];
        a0[0] += hA[0] * wv; a0[1] += hA[1] * wv;
        a0[2] += hA[2] * wv; a0[3] += hA[3] * wv;
        a0[4] += hB[0] * wv; a0[5] += hB[1] * wv;
        a0[6] += hB[2] * wv; a0[7] += hB[3] * wv;
    }
    {
        const float b1v = b1[y * DH2 + t];
        const float w2v = W2[y * DH2 + t];
        float p[8];
        #pragma unroll
        for (int m = 0; m < 8; ++m)
            p[m] = fmaxf(a0[m] + b1v, 0.f) * w2v;
        #pragma unroll
        for (int m = 0; m < 8; ++m) {
            float v = p[m];
            for (int off = 32; off > 0; off >>= 1) v += __shfl_down(v, off);
            if (lane == 0) red[w][m] = v;
        }
    }
    __syncthreads();
    if (t < ROWS8) {
        float s = b2[y];
        #pragma unroll
        for (int ww = 0; ww < 8; ++ww) s += red[ww][t];
        out[(size_t)(b0 + t) * NY + y] = s;
    }
}

extern "C" void kernel_launch(void* const* d_in, const int* in_sizes, int n_in,
                              void* d_out, int out_size, void* d_ws, size_t ws_size,
                              hipStream_t stream) {
    const float* x   = (const float*)d_in[0];
    const float* w_x = (const float*)d_in[1];
    const float* w_h = (const float*)d_in[2];
    const float* b   = (const float*)d_in[3];
    const float* W1  = (const float*)d_in[4];
    const float* b1  = (const float*)d_in[5];
    const float* W2  = (const float*)d_in[6];
    const float* b2  = (const float*)d_in[7];
    float* out = (float*)d_out;

    dim3 grid(256), block(512);
    hipLaunchKernelGGL(cwrnn_mfma7, grid, block, 0, stream,
                       x, w_x, w_h, b, W1, b1, W2, b2, out);
}

// Round 9
// 144.654 us; speedup vs baseline: 7.7768x; 1.2110x over previous
//
#include <hip/hip_runtime.h>
#include <math.h>

// Clockwork RNN, B=512 T=192 DX=32 DH1=256 DH2=512 DY=4
// R8 = R7 with SINGLE fp16 W (no hi/lo split): |w|<=1/16 so fp16 rel err
// 2.4e-4 ~ the fp16-h quant noise R7 already carries (measured 9.8e-4 total).
// Halves the MFMA floor (24.75 -> 12.4 per wave per step) and W registers.
// Chains: k-split accumulators (kt0-3 -> a, kt4-7+x -> b) keep 2 independent
// MFMA chains per tile for latency hiding.
// Structure otherwise R7: 256 blocks x 512 thr (2 waves/SIMD, all CUs),
// h fp16 single array in LDS (broadcast B-fragment, no cross-lane merge),
// double-buffered h + clockwork carry, 1 barrier/step, x register prefetch,
// W fragments FULLY UNROLLED into registers (R2 scratch-demotion lesson).

#define TT    192
#define DXX   32
#define DH1   256
#define DH2   512
#define NY    4
#define ROWS8 8
#define PADK  264   // row stride in fp16 elems (528B)

typedef _Float16 f16x8 __attribute__((ext_vector_type(8)));
typedef __attribute__((ext_vector_type(4))) float f32x4;
typedef __attribute__((ext_vector_type(2))) int   i32x2;
typedef __attribute__((ext_vector_type(4))) int   i32x4;

template<int N> struct IC { static constexpr int v = N; };

__device__ __forceinline__ unsigned pkrtz(float a, float b) {
    unsigned d;
    asm("v_cvt_pkrtz_f16_f32 %0, %1, %2" : "=v"(d) : "v"(a), "v"(b));
    return d;   // lo16 = f16(a), hi16 = f16(b), RTZ (x input only)
}
__device__ __forceinline__ unsigned short f16bits(_Float16 h) {
    union { _Float16 f; unsigned short u; } c; c.f = h; return c.u;
}
__device__ __forceinline__ float fast_tanh(float v) {
    float t = __builtin_amdgcn_exp2f(v * 2.885390081777927f);
    return fmaf(-2.f, __builtin_amdgcn_rcpf(t + 1.f), 1.f);
}

__global__ __launch_bounds__(512, 2) void cwrnn_mfma8(
    const float* __restrict__ x,     // [B,T,DX]
    const float* __restrict__ w_x,   // [DY,DX,DH1]
    const float* __restrict__ w_h,   // [DY,DH1,DH1]
    const float* __restrict__ bias,  // [DY,DH1]
    const float* __restrict__ W1,    // [DY,DH1,DH2]
    const float* __restrict__ b1,    // [DY,DH2]
    const float* __restrict__ W2,    // [DY,DH2]
    const float* __restrict__ b2,    // [DY]
    float* __restrict__ out)         // [B,DY]
{
    __shared__ _Float16 hb[2][ROWS8 * PADK];   // h fp16, [buf][row][k]
    __shared__ float red[8][ROWS8];
    __shared__ float scratch[DXX * DH1];       // 32KB staging; reused as hT

    const int t    = threadIdx.x;
    const int lane = t & 63;
    const int w    = t >> 6;        // wave 0..7; tiles {w, 8+w}
    const int r    = lane & 15;
    const int rb   = r & 7;         // batch row (r and r+8 duplicate)
    const int q    = lane >> 4;
    const int y    = blockIdx.x & 3;
    const int b0   = (blockIdx.x >> 2) * ROWS8;

    const float* wx_g = w_x + (size_t)y * DXX * DH1;
    const float* wh_g = w_h + (size_t)y * DH1 * DH1;

    for (int i = t; i < ROWS8 * PADK; i += 512) hb[0][i] = (_Float16)0.f;

    // ---- w_x fragments: wave w -> tiles {w, 8+w}; single fp16 ----
    f16x8 wxf[2];
    for (int i = t * 4; i < DXX * DH1; i += 2048)
        *(f32x4*)&scratch[i] = *(const f32x4*)&wx_g[i];
    __syncthreads();
    #pragma unroll
    for (int m = 0; m < 2; ++m) {
        f16x8 vh;
        #pragma unroll
        for (int jj = 0; jj < 8; ++jj)
            vh[jj] = (_Float16)scratch[(q * 8 + jj) * DH1 + ((m * 8 + w) << 4) + r];
        wxf[m] = vh;
    }
    __syncthreads();

    // ---- w_h fragments: 8 ktiles x 2 mtiles, single fp16. FULLY UNROLLED
    // (runtime index -> scratch demotion; R2 lesson). ----
    f16x8 whf[8][2];
    #pragma unroll
    for (int kt = 0; kt < 8; ++kt) {
        for (int i = t * 4; i < 32 * DH1; i += 2048)
            *(f32x4*)&scratch[i] = *(const f32x4*)&wh_g[kt * 32 * DH1 + i];
        __syncthreads();
        #pragma unroll
        for (int m = 0; m < 2; ++m) {
            f16x8 vh;
            #pragma unroll
            for (int jj = 0; jj < 8; ++jj)
                vh[jj] = (_Float16)scratch[(q * 8 + jj) * DH1 + ((m * 8 + w) << 4) + r];
            whf[kt][m] = vh;
        }
        __syncthreads();
    }

    f32x4 bias4[2];
    #pragma unroll
    for (int m = 0; m < 2; ++m)
        #pragma unroll
        for (int rr = 0; rr < 4; ++rr)
            bias4[m][rr] = bias[y * DH1 + ((m * 8 + w) << 4) + q * 4 + rr];

    // ---- per-lane LDS pointers ----
    const _Float16* hrd[2] = { &hb[0][rb * PADK] + q * 8,
                               &hb[1][rb * PADK] + q * 8 };
    _Float16* hwr[2] = { &hb[0][rb * PADK + w * 16 + q * 4],
                         &hb[1][rb * PADK + w * 16 + q * 4] };

    const float* xrow = x + (size_t)(b0 + rb) * TT * DXX + q * 8;
    f32x4 cxa = *(const f32x4*)&xrow[0];
    f32x4 cxb = *(const f32x4*)&xrow[4];

    // ---- one recurrence step ----
    auto body = [&](int j, auto SC, int cur) {
        constexpr int S  = SC.v;                       // 0:NC=128 1:192 2:256
        constexpr int NF = (S == 0) ? 16 : (S == 1) ? 24 : 32;
        const bool m1act = (S == 2) || (S == 1 && w < 4);

        // prefetch next step's x
        const int jn = (j + 1 < TT) ? j + 1 : j;
        const f32x4 pxa = *(const f32x4*)&xrow[jn * DXX];
        const f32x4 pxb = *(const f32x4*)&xrow[jn * DXX + 4];

        // x B-fragment, fp16 (quad-uniform feature mask)
        f16x8 xf;
        if (q * 8 < NF) {
            union { i32x4 i; f16x8 h; } ux;
            ux.i = (i32x4){ (int)pkrtz(cxa[0], cxa[1]), (int)pkrtz(cxa[2], cxa[3]),
                            (int)pkrtz(cxb[0], cxb[1]), (int)pkrtz(cxb[2], cxb[3]) };
            xf = ux.h;
        } else {
            xf = (f16x8)(_Float16)0.f;
        }

        const _Float16* hp = hrd[cur];

        // k-split accumulators: kt0-3 -> a, kt4-7 + x -> b (2 indep chains)
        f32x4 a0a = bias4[0], a0b = {0,0,0,0};
        f32x4 a1a = bias4[1], a1b = {0,0,0,0};

        #pragma unroll
        for (int kt = 0; kt < 4; ++kt) {
            const f16x8 hv0 = *(const f16x8*)(hp + kt * 32);
            const f16x8 hv1 = *(const f16x8*)(hp + (kt + 4) * 32);
            a0a = __builtin_amdgcn_mfma_f32_16x16x32_f16(whf[kt][0], hv0, a0a, 0, 0, 0);
            a0b = __builtin_amdgcn_mfma_f32_16x16x32_f16(whf[kt + 4][0], hv1, a0b, 0, 0, 0);
            if (m1act) {
                a1a = __builtin_amdgcn_mfma_f32_16x16x32_f16(whf[kt][1], hv0, a1a, 0, 0, 0);
                a1b = __builtin_amdgcn_mfma_f32_16x16x32_f16(whf[kt + 4][1], hv1, a1b, 0, 0, 0);
            }
        }
        a0b = __builtin_amdgcn_mfma_f32_16x16x32_f16(wxf[0], xf, a0b, 0, 0, 0);
        if (m1act)
            a1b = __builtin_amdgcn_mfma_f32_16x16x32_f16(wxf[1], xf, a1b, 0, 0, 0);

        // ---- epilogue tile 0: s = a + b, tanh, RNE pack, write ----
        {
            const f32x4 s = a0a + a0b;
            const unsigned short h0 = f16bits((_Float16)fast_tanh(s[0]));
            const unsigned short h1 = f16bits((_Float16)fast_tanh(s[1]));
            const unsigned short h2 = f16bits((_Float16)fast_tanh(s[2]));
            const unsigned short h3 = f16bits((_Float16)fast_tanh(s[3]));
            if (r < 8) {
                *(i32x2*)(hwr[cur ^ 1]) =
                    (i32x2){ (int)(h0 | ((unsigned)h1 << 16)),
                             (int)(h2 | ((unsigned)h3 << 16)) };
            }
        }
        // ---- epilogue tile 1 (or clockwork carry) ----
        if (m1act) {
            const f32x4 s = a1a + a1b;
            const unsigned short h0 = f16bits((_Float16)fast_tanh(s[0]));
            const unsigned short h1 = f16bits((_Float16)fast_tanh(s[1]));
            const unsigned short h2 = f16bits((_Float16)fast_tanh(s[2]));
            const unsigned short h3 = f16bits((_Float16)fast_tanh(s[3]));
            if (r < 8) {
                *(i32x2*)(hwr[cur ^ 1] + 128) =
                    (i32x2){ (int)(h0 | ((unsigned)h1 << 16)),
                             (int)(h2 | ((unsigned)h3 << 16)) };
            }
        } else {
            if (r < 8)
                *(i32x2*)(hwr[cur ^ 1] + 128) = *(const i32x2*)(hwr[cur] + 128);
        }
        __syncthreads();
        cxa = pxa; cxb = pxb;
    };

    // ---- main loop ----
    for (int j = 0; j < TT; j += 4) {
        body(j + 0, IC<0>{}, 0);   // jp odd           -> NC=128
        body(j + 1, IC<1>{}, 1);   // jp%2==0, %4!=0   -> NC=192
        body(j + 2, IC<0>{}, 0);   // jp odd           -> NC=128
        body(j + 3, IC<2>{}, 1);   // jp%4==0          -> NC=256
    }
    // final h in buffer 0

    // ---- rebuild h fp32, transposed [k][row] ----
    float* hT = scratch;
    for (int i = t; i < DH1 * ROWS8; i += 512) {
        const int row = i & 7, k = i >> 3;
        hT[k * ROWS8 + row] = (float)hb[0][row * PADK + k];
    }
    __syncthreads();

    // ---- head: hid = relu(h @ W1 + b1); y = hid @ W2 + b2 ----
    const float* W1_g = W1 + (size_t)y * DH1 * DH2;
    float a0[8];
    #pragma unroll
    for (int m = 0; m < 8; ++m) a0[m] = 0.f;
    for (int k = 0; k < DH1; ++k) {
        const float wv = W1_g[(size_t)k * DH2 + t];
        const f32x4 hA = *(const f32x4*)&hT[k * ROWS8];
        const f32x4 hB = *(const f32x4*)&hT[k * ROWS8 + 4];
        a0[0] += hA[0] * wv; a0[1] += hA[1] * wv;
        a0[2] += hA[2] * wv; a0[3] += hA[3] * wv;
        a0[4] += hB[0] * wv; a0[5] += hB[1] * wv;
        a0[6] += hB[2] * wv; a0[7] += hB[3] * wv;
    }
    {
        const float b1v = b1[y * DH2 + t];
        const float w2v = W2[y * DH2 + t];
        float p[8];
        #pragma unroll
        for (int m = 0; m < 8; ++m)
            p[m] = fmaxf(a0[m] + b1v, 0.f) * w2v;
        #pragma unroll
        for (int m = 0; m < 8; ++m) {
            float v = p[m];
            for (int off = 32; off > 0; off >>= 1) v += __shfl_down(v, off);
            if (lane == 0) red[w][m] = v;
        }
    }
    __syncthreads();
    if (t < ROWS8) {
        float s = b2[y];
        #pragma unroll
        for (int ww = 0; ww < 8; ++ww) s += red[ww][t];
        out[(size_t)(b0 + t) * NY + y] = s;
    }
}

extern "C" void kernel_launch(void* const* d_in, const int* in_sizes, int n_in,
                              void* d_out, int out_size, void* d_ws, size_t ws_size,
                              hipStream_t stream) {
    const float* x   = (const float*)d_in[0];
    const float* w_x = (const float*)d_in[1];
    const float* w_h = (const float*)d_in[2];
    const float* b   = (const float*)d_in[3];
    const float* W1  = (const float*)d_in[4];
    const float* b1  = (const float*)d_in[5];
    const float* W2  = (const float*)d_in[6];
    const float* b2  = (const float*)d_in[7];
    float* out = (float*)d_out;

    dim3 grid(256), block(512);
    hipLaunchKernelGGL(cwrnn_mfma8, grid, block, 0, stream,
                       x, w_x, w_h, b, W1, b1, W2, b2, out);
}